// Round 2
// baseline (122.972 us; speedup 1.0000x reference)
//
#include <hip/hip_runtime.h>
#include <hip/hip_bf16.h>
#include <stdint.h>

// R2NPropositionalLayer: per (b,t) with i,j,k = idx arrays[t]:
//   emb = 1 - (1 - x_i*x_j) * x_k
//   bb  = ((c_i && c_j) || !c_k) ? 1.0f : 0.0f
// c_bool arrives as int32 (harness casts bool -> int32) — round-1 fix.
// lane = t (T == 64 == wave size) -> coalesced output stores; wave = row b.

__global__ __launch_bounds__(256) void r2n_prop_kernel(
    const float* __restrict__ x,
    const int* __restrict__ cb,       // bool pushed as int32
    const int* __restrict__ i_idx,
    const int* __restrict__ j_idx,
    const int* __restrict__ k_idx,
    float* __restrict__ emb,
    float* __restrict__ bb,
    int C, int T, long long BT)
{
    long long gid = (long long)blockIdx.x * blockDim.x + threadIdx.x;
    if (gid >= BT) return;
    int t = (int)(gid % T);
    long long b = gid / T;

    int i = i_idx[t];
    int j = j_idx[t];
    int k = k_idx[t];

    const float* xr = x  + b * (long long)C;
    const int*   cr = cb + b * (long long)C;

    float xi = xr[i];
    float xj = xr[j];
    float xk = xr[k];
    float e = fmaf(-(1.0f - xi * xj), xk, 1.0f);  // 1 - (1 - xi*xj)*xk

    bool bi = cr[i] != 0;
    bool bj = cr[j] != 0;
    bool bk = cr[k] != 0;
    float bbv = ((bi && bj) || !bk) ? 1.0f : 0.0f;

    emb[gid] = e;
    bb[gid]  = bbv;
}

extern "C" void kernel_launch(void* const* d_in, const int* in_sizes, int n_in,
                              void* d_out, int out_size, void* d_ws, size_t ws_size,
                              hipStream_t stream)
{
    const float* x    = (const float*)d_in[0];
    const int*   cb   = (const int*)d_in[1];
    const int*   iidx = (const int*)d_in[2];
    const int*   jidx = (const int*)d_in[3];
    const int*   kidx = (const int*)d_in[4];

    float* emb = (float*)d_out;

    int T = in_sizes[2];                      // 64
    long long BT = (long long)out_size / 2;   // B*T
    long long B  = BT / T;
    int C = (int)((long long)in_sizes[0] / B); // 256

    float* bb = emb + BT;

    const int block = 256;
    long long nblocks = (BT + block - 1) / block;

    r2n_prop_kernel<<<(uint32_t)nblocks, block, 0, stream>>>(
        x, cb, iidx, jidx, kidx, emb, bb, C, T, BT);
}

// Round 3
// 103.795 us; speedup vs baseline: 1.1848x; 1.1848x over previous
//
#include <hip/hip_runtime.h>
#include <hip/hip_bf16.h>
#include <stdint.h>

// R2NPropositionalLayer: per (b,t) with i,j,k = idx arrays[t]:
//   emb = 1 - (1 - x_i*x_j) * x_k
//   bb  = ((c_i && c_j) || !c_k) ? 1.0f : 0.0f
// c_bool arrives as int32. lane = t (T==64==wave) -> coalesced stores.
// Round 3: runtime indices satisfy j==i+1, k==i+2 -> guarded fast path with
// 12-byte contiguous loads (dwordx3) instead of 3 separate dword gathers,
// and 4 rows per thread for load-level ILP. Fallback keeps generic gather.

#define ROWS_PER_WAVE 4

__global__ __launch_bounds__(256) void r2n_prop_kernel(
    const float* __restrict__ x,
    const int* __restrict__ cb,       // bool pushed as int32
    const int* __restrict__ i_idx,
    const int* __restrict__ j_idx,
    const int* __restrict__ k_idx,
    float* __restrict__ emb,
    float* __restrict__ bb,
    int C, int T, long long Brows)
{
    int lane = threadIdx.x & 63;
    int wave = threadIdx.x >> 6;
    long long rowBase = ((long long)blockIdx.x * 4 + wave) * ROWS_PER_WAVE;

    int t = lane;
    if (t >= T) return;               // T==64 in practice; guard for safety

    int i = i_idx[t];
    int j = j_idx[t];
    int k = k_idx[t];

    bool fast = (j == i + 1) && (k == i + 2);

    if (fast) {
        #pragma unroll
        for (int r = 0; r < ROWS_PER_WAVE; ++r) {
            long long b = rowBase + r;
            if (b >= Brows) break;
            const float* xr = x  + b * (long long)C;
            const int*   cr = cb + b * (long long)C;

            float xv[3];
            int   cv[3];
            __builtin_memcpy(xv, xr + i, 12);   // dwordx3, contiguous per lane
            __builtin_memcpy(cv, cr + i, 12);

            float e = fmaf(-(1.0f - xv[0] * xv[1]), xv[2], 1.0f);
            float bbv = (((cv[0] != 0) && (cv[1] != 0)) || (cv[2] == 0)) ? 1.0f : 0.0f;

            long long o = b * (long long)T + t;
            emb[o] = e;
            bb[o]  = bbv;
        }
    } else {
        #pragma unroll
        for (int r = 0; r < ROWS_PER_WAVE; ++r) {
            long long b = rowBase + r;
            if (b >= Brows) break;
            const float* xr = x  + b * (long long)C;
            const int*   cr = cb + b * (long long)C;

            float xi = xr[i], xj = xr[j], xk = xr[k];
            int   ci = cr[i], cj = cr[j], ck = cr[k];

            float e = fmaf(-(1.0f - xi * xj), xk, 1.0f);
            float bbv = (((ci != 0) && (cj != 0)) || (ck == 0)) ? 1.0f : 0.0f;

            long long o = b * (long long)T + t;
            emb[o] = e;
            bb[o]  = bbv;
        }
    }
}

extern "C" void kernel_launch(void* const* d_in, const int* in_sizes, int n_in,
                              void* d_out, int out_size, void* d_ws, size_t ws_size,
                              hipStream_t stream)
{
    const float* x    = (const float*)d_in[0];
    const int*   cb   = (const int*)d_in[1];
    const int*   iidx = (const int*)d_in[2];
    const int*   jidx = (const int*)d_in[3];
    const int*   kidx = (const int*)d_in[4];

    float* emb = (float*)d_out;

    int T = in_sizes[2];                      // 64
    long long BT = (long long)out_size / 2;   // B*T
    long long B  = BT / T;
    int C = (int)((long long)in_sizes[0] / B); // 256

    float* bb = emb + BT;

    // 4 waves/block, ROWS_PER_WAVE rows per wave
    long long rowsPerBlock = 4LL * ROWS_PER_WAVE;
    long long nblocks = (B + rowsPerBlock - 1) / rowsPerBlock;

    r2n_prop_kernel<<<(uint32_t)nblocks, 256, 0, stream>>>(
        x, cb, iidx, jidx, kidx, emb, bb, C, T, B);
}